// Round 10
// baseline (117.162 us; speedup 1.0000x reference)
//
#include <hip/hip_runtime.h>
#include <hip/hip_bf16.h>
#include <cstdint>

typedef __attribute__((ext_vector_type(8))) short short8;
typedef __attribute__((ext_vector_type(8))) unsigned short ushort8;
typedef __attribute__((ext_vector_type(4))) float f32x4;

#define B_TRIALS 256
#define F_BINS   100
#define N_UNITS  512
#define P_CH     512
#define G_SESS   10
#define H_DIM    1024  // 2N
#define TOT_ROWS (B_TRIALS * F_BINS)  // 25600
#define NT_PAD   216                  // 128-row tiles padded; 216 = 27 per XCD

// prep kernel block ranges (planner + cast_x + W1 transpose; W2 transpose rides in gemm1)
#define PREP_CASTX_BLOCKS 2048
#define PREP_W1_BLOCKS    5120   // (1024/32) x (512/32) x 10
#define PREP_TOTAL (1 + PREP_CASTX_BLOCKS + PREP_W1_BLOCKS)
#define W2T_BLOCKS        5120   // (512/32) x (1024/32) x 10

// f32 -> bf16 round-to-nearest-even (finite inputs)
__device__ __forceinline__ unsigned short f2bf(float f) {
  unsigned int u = __builtin_bit_cast(unsigned int, f);
  u += 0x7fffu + ((u >> 16) & 1u);
  return (unsigned short)(u >> 16);
}

// async global->LDS, 16B per lane; lds dest must be wave-uniform base (+lane*16 by HW)
__device__ __forceinline__ void gload16(const void* gsrc, void* ldst) {
  __builtin_amdgcn_global_load_lds(
      (const __attribute__((address_space(1))) unsigned int*)gsrc,
      (__attribute__((address_space(3))) unsigned int*)ldst, 16, 0, 0);
}

__device__ __forceinline__ void transpose_tile(const float* __restrict__ src,
                                               unsigned short* __restrict__ dst,
                                               int K, int N, int g, int n0, int k0,
                                               float (*tile)[33]) {
  const float* s = src + (size_t)g * K * N;
  unsigned short* d = dst + (size_t)g * N * K;
  int t = threadIdx.x;
  int r = t >> 3, c = (t & 7) * 4;
  float4 v = *(const float4*)(s + (size_t)(k0 + r) * N + n0 + c);
  tile[r][c + 0] = v.x; tile[r][c + 1] = v.y;
  tile[r][c + 2] = v.z; tile[r][c + 3] = v.w;
  __syncthreads();
  ushort4 o;
  o.x = f2bf(tile[c + 0][r]);
  o.y = f2bf(tile[c + 1][r]);
  o.z = f2bf(tile[c + 2][r]);
  o.w = f2bf(tile[c + 3][r]);
  *(ushort4*)(d + (size_t)(n0 + r) * K + k0 + c) = o;
}

// ---------------- prep: planner | cast_x | W1 transpose ----------------
__global__ void prep(const float* __restrict__ x, const int* __restrict__ eid,
                     const float* __restrict__ W1,
                     unsigned short* __restrict__ xb,
                     unsigned short* __restrict__ W1t,
                     int* __restrict__ rowmap, int* __restrict__ tile_meta) {
  __shared__ float tile[32][33];
  __shared__ int e[B_TRIALS], cnt[G_SESS], off[G_SESS], groff[G_SESS + 1], perm[B_TRIALS];
  const int bid = blockIdx.x;
  const int t = threadIdx.x;

  if (bid == 0) {
    // planner: stable counting sort of trials by eid, 128-row tiles
    e[t] = eid[t];
    if (t < G_SESS) cnt[t] = 0;
    __syncthreads();
    atomicAdd(&cnt[e[t]], 1);
    __syncthreads();
    if (t == 0) {
      int s = 0, r = 0;
      for (int g = 0; g < G_SESS; g++) {
        off[g] = s; s += cnt[g];
        groff[g] = r; r += cnt[g] * F_BINS;
      }
      groff[G_SESS] = r;
    }
    __syncthreads();
    int g = e[t], rank = 0;
    for (int j = 0; j < t; j++) rank += (e[j] == g);
    perm[off[g] + rank] = t;
    __syncthreads();
    for (int i = t; i < TOT_ROWS; i += 256) {
      int gg = 0;
      while (gg + 1 < G_SESS && i >= groff[gg + 1]) gg++;
      int loc = i - groff[gg];
      rowmap[i] = perm[off[gg] + loc / F_BINS] * F_BINS + loc % F_BINS;
    }
    if (t == 0) {
      int ti = 0;
      for (int g2 = 0; g2 < G_SESS; g2++) {
        int rows = cnt[g2] * F_BINS;
        int base = groff[g2];
        for (int r0 = 0; r0 < rows; r0 += 128) {
          tile_meta[ti * 3 + 0] = g2;
          tile_meta[ti * 3 + 1] = base + r0;
          tile_meta[ti * 3 + 2] = (rows - r0 < 128) ? (rows - r0) : 128;
          ti++;
        }
      }
      for (; ti < NT_PAD; ti++) {
        tile_meta[ti * 3 + 0] = -1; tile_meta[ti * 3 + 1] = 0; tile_meta[ti * 3 + 2] = 0;
      }
    }
  } else if (bid <= PREP_CASTX_BLOCKS) {
    // cast_x: f32 -> bf16, 8 elems/thread/iter, grid-stride
    const int n8 = B_TRIALS * F_BINS * N_UNITS / 8;
    int i = (bid - 1) * 256 + t;
    const int stride = PREP_CASTX_BLOCKS * 256;
    for (; i < n8; i += stride) {
      float4 v0 = ((const float4*)x)[(size_t)i * 2];
      float4 v1 = ((const float4*)x)[(size_t)i * 2 + 1];
      ushort8 w;
      w[0] = f2bf(v0.x); w[1] = f2bf(v0.y); w[2] = f2bf(v0.z); w[3] = f2bf(v0.w);
      w[4] = f2bf(v1.x); w[5] = f2bf(v1.y); w[6] = f2bf(v1.z); w[7] = f2bf(v1.w);
      ((ushort8*)xb)[i] = w;
    }
  } else {
    // W1 [g][512][1024] -> W1t [g][1024][512]
    int tt = bid - 1 - PREP_CASTX_BLOCKS;
    int n0 = (tt & 31) * 32, k0 = ((tt >> 5) & 15) * 32, g = tt >> 9;
    transpose_tile(W1, W1t, N_UNITS, H_DIM, g, n0, k0, tile);
  }
}

// ---------------- grouped 128x256 GEMM, BK=64, single-buffer, wave tile 64x128 ----------------
// 256 threads / 4 waves (2x2); wave owns 64 rows x 128 cols (acc 4x8 = 42.7 FLOP/LDS-byte,
// vs 32 at 64x64 which saturates the 128 B/cyc LDS ceiling). LDS 48 KiB single-buffered,
// launch_bounds(256,2) -> 2 blocks/CU co-resident (R9's occupancy mechanism).
// Loop (R9-proven): {syncthreads | 12 gload16 | vmcnt(0)+lgkmcnt(0) | syncthreads | compute}.
// XCD-chunked grid over the first NT_PAD*NC blocks; with XW2, extra blocks transpose W2.

template<int KTOT, int NOUT, int NC, bool IS2, bool XW2>
__global__ __launch_bounds__(256, 2) void gemm_grouped(
    const unsigned short* __restrict__ Asrc,
    const unsigned short* __restrict__ Wt,
    const float* __restrict__ bias,
    const int* __restrict__ rowmap,
    const int* __restrict__ tile_meta,
    unsigned short* __restrict__ hout,
    float* __restrict__ out,
    const float* __restrict__ W2src,
    unsigned short* __restrict__ W2dst) {
  __shared__ __align__(16) unsigned short Ash[128 * 64];  // 16 KiB
  __shared__ __align__(16) unsigned short Bsh[256 * 64];  // 32 KiB

  constexpr int GEMM_BLOCKS = NT_PAD * NC;
  if (XW2 && blockIdx.x >= GEMM_BLOCKS) {
    // W2 [g][1024][512] -> W2t [g][512][1024], overlapped with gemm1 compute
    int tt = blockIdx.x - GEMM_BLOCKS;
    int n0 = (tt & 15) * 32, k0 = ((tt >> 4) & 31) * 32, g = tt >> 9;
    transpose_tile(W2src, W2dst, H_DIM, P_CH, g, n0, k0, (float(*)[33])Ash);
    return;
  }

  // bijective XCD-chunked remap (GEMM_BLOCKS % 8 == 0)
  const int wg = blockIdx.x;
  const int xcd = wg & 7, slot = wg >> 3;
  const int mt = xcd * (NT_PAD / 8) + slot / NC;
  const int nc = slot % NC;

  const int g = tile_meta[mt * 3 + 0];
  if (g < 0) return;
  const int row0 = tile_meta[mt * 3 + 1];
  const int valid = tile_meta[mt * 3 + 2];
  const int ncol0 = nc * 256;

  const int tid = threadIdx.x;
  const int lane = tid & 63;
  const int w = tid >> 6;
  const int wm = w >> 1, wn = w & 1;        // 2x2 wave grid; wave owns 64 x 128
  const int lr = lane & 15, lq = lane >> 4;

  // staging sources (fixed over K; +64 elems per K-tile)
  // chunk c = it*256 + tid: row/col = it*32 + (tid>>3), q = tid&7, ks = q ^ (row&7)
  const unsigned short* Wg = Wt + (size_t)g * NOUT * KTOT + (size_t)ncol0 * KTOT;
  const unsigned short* aptr[4];
  const unsigned short* bptr[8];
  {
    int rbase = tid >> 3, q = tid & 7;
#pragma unroll
    for (int it = 0; it < 4; it++) {
      int row = it * 32 + rbase;
      int ks = (q ^ (row & 7)) * 8;
      int grow = row0 + row; if (grow > TOT_ROWS - 1) grow = TOT_ROWS - 1;
      int sr = IS2 ? grow : rowmap[grow];
      aptr[it] = Asrc + (size_t)sr * KTOT + ks;
    }
#pragma unroll
    for (int it = 0; it < 8; it++) {
      int col = it * 32 + rbase;
      int ks = (q ^ (col & 7)) * 8;
      bptr[it] = Wg + (size_t)col * KTOT + ks;
    }
  }

  f32x4 acc[4][8];
#pragma unroll
  for (int m = 0; m < 4; m++)
#pragma unroll
    for (int n = 0; n < 8; n++) acc[m][n] = (f32x4){0.f, 0.f, 0.f, 0.f};

  constexpr int NK = KTOT / 64;

  for (int t = 0; t < NK; ++t) {
    const size_t ko = (size_t)t * 64;
    __syncthreads();  // all waves' reads of previous tile complete before overwrite
#pragma unroll
    for (int it = 0; it < 4; it++)
      gload16(aptr[it] + ko, &Ash[(it * 256 + (tid & 192)) * 8]);
#pragma unroll
    for (int it = 0; it < 8; it++)
      gload16(bptr[it] + ko, &Bsh[(it * 256 + (tid & 192)) * 8]);
    asm volatile("s_waitcnt vmcnt(0) lgkmcnt(0)" ::: "memory");
    __syncthreads();  // publish staged tile

#pragma unroll
    for (int kk = 0; kk < 2; kk++) {
      int kslot = kk * 4 + lq;
      short8 av[4];
#pragma unroll
      for (int m = 0; m < 4; m++) {
        int row = wm * 64 + m * 16 + lr;
        av[m] = *(const short8*)&Ash[row * 64 + ((kslot ^ (row & 7)) * 8)];
      }
#pragma unroll
      for (int nh = 0; nh < 2; nh++) {   // bv in halves caps live registers
        short8 bv[4];
#pragma unroll
        for (int n = 0; n < 4; n++) {
          int col = wn * 128 + nh * 64 + n * 16 + lr;
          bv[n] = *(const short8*)&Bsh[col * 64 + ((kslot ^ (col & 7)) * 8)];
        }
#pragma unroll
        for (int n = 0; n < 4; n++)
#pragma unroll
          for (int m = 0; m < 4; m++)
            acc[m][nh * 4 + n] =
                __builtin_amdgcn_mfma_f32_16x16x32_bf16(av[m], bv[n], acc[m][nh * 4 + n], 0, 0, 0);
      }
    }
  }

  // epilogue: acc[m][j] -> col = ncol0 + wn*128 + (j>>2)*64 + (j&3)*16 + lr
  float bv8[8];
#pragma unroll
  for (int j = 0; j < 8; j++)
    bv8[j] = bias[(size_t)g * NOUT + ncol0 + wn * 128 + (j >> 2) * 64 + (j & 3) * 16 + lr];

  if (!IS2) {
#pragma unroll
    for (int m = 0; m < 4; m++)
#pragma unroll
      for (int r4 = 0; r4 < 4; r4++) {
        int lrow = wm * 64 + m * 16 + lq * 4 + r4;
        if (lrow < valid) {
          size_t base = (size_t)(row0 + lrow) * H_DIM + ncol0 + wn * 128 + lr;
#pragma unroll
          for (int j = 0; j < 8; j++) {
            float v = acc[m][j][r4] + bv8[j];
            v = v / (1.0f + fabsf(v));
            hout[base + (j >> 2) * 64 + (j & 3) * 16] = f2bf(v);
          }
        }
      }
  } else {
#pragma unroll
    for (int m = 0; m < 4; m++)
#pragma unroll
      for (int r4 = 0; r4 < 4; r4++) {
        int lrow = wm * 64 + m * 16 + lq * 4 + r4;
        if (lrow < valid) {
          int orow = rowmap[row0 + lrow];
          size_t base = (size_t)orow * P_CH + ncol0 + wn * 128 + lr;
#pragma unroll
          for (int j = 0; j < 8; j++)
            out[base + (j >> 2) * 64 + (j & 3) * 16] = acc[m][j][r4] + bv8[j];
        }
      }
  }
}

extern "C" void kernel_launch(void* const* d_in, const int* in_sizes, int n_in,
                              void* d_out, int out_size, void* d_ws, size_t ws_size,
                              hipStream_t stream) {
  const float* x  = (const float*)d_in[0];
  const int* eid  = (const int*)d_in[1];
  const float* W1 = (const float*)d_in[2];
  const float* b1 = (const float*)d_in[3];
  const float* W2 = (const float*)d_in[4];
  const float* b2 = (const float*)d_in[5];
  float* out = (float*)d_out;

  unsigned short* W1t = (unsigned short*)d_ws;                       // [10][1024][512] bf16
  unsigned short* W2t = W1t + (size_t)G_SESS * H_DIM * N_UNITS;      // [10][512][1024] bf16
  unsigned short* h   = W2t + (size_t)G_SESS * P_CH * H_DIM;         // [25600][1024] bf16 (compact)
  int* rowmap    = (int*)(h + (size_t)TOT_ROWS * H_DIM);             // [25600]
  int* tile_meta = rowmap + TOT_ROWS;                                // [216][3]
  unsigned short* xb = (unsigned short*)d_out;                       // [256][100][512] bf16 (dead before gemm2 writes)

  prep<<<PREP_TOTAL, 256, 0, stream>>>(x, eid, W1, xb, W1t, rowmap, tile_meta);
  // gemm1 (NC=4 -> 864 GEMM blocks) + 5120 W2-transpose blocks overlapped
  gemm_grouped<N_UNITS, H_DIM, 4, false, true><<<NT_PAD * 4 + W2T_BLOCKS, 256, 0, stream>>>(
      xb, W1t, b1, rowmap, tile_meta, h, out, W2, W2t);
  gemm_grouped<H_DIM, P_CH, 2, true, false><<<NT_PAD * 2, 256, 0, stream>>>(
      h, W2t, b2, rowmap, tile_meta, h, out, nullptr, nullptr);
}